// Round 8
// baseline (227.790 us; speedup 1.0000x reference)
//
#include <hip/hip_runtime.h>
#include <hip/hip_bf16.h>

#define BATCH 16384
#define NH 1024
#define NF 39
#define CCLD 72
#define KX 2432      // GEMM1 K: [0:13 conts][13:16 pad0][16:1680 cate flat][1680:2421 pairs][2421:2432 pad0]
#define NPAIR 741

typedef __attribute__((ext_vector_type(8))) short bf16x8;
typedef __attribute__((ext_vector_type(4))) float f32x4;

typedef const __attribute__((address_space(1))) unsigned int* gptr_t;
typedef __attribute__((address_space(3))) unsigned int* lptr_t;

__device__ __forceinline__ float bf2f(unsigned short u) {
  union { unsigned int i; float f; } c; c.i = ((unsigned int)u) << 16; return c.f;
}
__device__ __forceinline__ unsigned short f2bf(float f) {
  union { float f; unsigned int i; } c; c.f = f;
  unsigned int r = c.i + 0x7FFFu + ((c.i >> 16) & 1u);
  return (unsigned short)(r >> 16);
}

// ---- merged W-prep: blocks [0,76) build W1t (row-remapped, M13 inline), [76,108) build W2t
__global__ __launch_bounds__(256) void wprep_kernel(
    const float* __restrict__ W1, const float* __restrict__ W2,
    const float* __restrict__ emb, unsigned short* __restrict__ W1t,
    unsigned short* __restrict__ W2t) {
  __shared__ float tile[32][33];
  int bx = blockIdx.x;
  int nb = blockIdx.y * 32;
  int tx = threadIdx.x & 31, ty = threadIdx.x >> 5;
  if (bx < KX / 32) {
    int kb = bx * 32;
#pragma unroll
    for (int i = 0; i < 32; i += 8) {
      int k = kb + ty + i;
      float v = 0.f;
      if (k < 13) {
        float s = 0.f;
#pragma unroll 8
        for (int d = 0; d < 64; ++d)
          s += emb[k * 64 + d] * W1[(size_t)(k * 64 + d) * NH + nb + tx];
        v = s;
      } else if (k >= 16 && k < 1680) {
        v = W1[(size_t)(832 + k - 16) * NH + nb + tx];
      } else if (k >= 1680 && k < 1680 + NPAIR) {
        v = W1[(size_t)(2496 + k - 1680) * NH + nb + tx];
      }
      tile[ty + i][tx] = v;
    }
    __syncthreads();
#pragma unroll
    for (int i = 0; i < 32; i += 8)
      W1t[(size_t)(nb + ty + i) * KX + kb + tx] = f2bf(tile[tx][ty + i]);
  } else {
    int kb = (bx - KX / 32) * 32;
#pragma unroll
    for (int i = 0; i < 32; i += 8)
      tile[ty + i][tx] = W2[(size_t)(kb + ty + i) * NH + nb + tx];
    __syncthreads();
#pragma unroll
    for (int i = 0; i < 32; i += 8)
      W2t[(size_t)(nb + ty + i) * NH + kb + tx] = f2bf(tile[tx][ty + i]);
  }
}

// ---- features -> X' rows: [conts 13 | 0 | cate flat 1664 | pairs 741 | 0]
__global__ __launch_bounds__(256) void feature_kernel(
    const float* __restrict__ conts, const int* __restrict__ cates,
    const float* __restrict__ emb, unsigned short* __restrict__ X) {
  __shared__ unsigned short cc[4][48 * CCLD];
  __shared__ unsigned short pb[4][752];
  int wid = threadIdx.x >> 6, lane = threadIdx.x & 63;
  int b = (blockIdx.x << 2) | wid;
  unsigned short* my = cc[wid];
  unsigned short* pw = pb[wid];
  unsigned short* Xrow = X + (size_t)b * KX;

#pragma unroll
  for (int f = 0; f < 13; ++f)
    my[f * CCLD + lane] = f2bf(emb[f * 64 + lane] * conts[b * 13 + f]);
#pragma unroll 2
  for (int j = 0; j < 26; ++j) {
    int idx = cates[b * 26 + j];
    my[(13 + j) * CCLD + lane] = f2bf(emb[(size_t)idx * 64 + lane]);
  }
#pragma unroll
  for (int f = NF; f < 48; ++f) my[f * CCLD + lane] = 0;
  if (lane < 16) Xrow[lane] = (lane < 13) ? f2bf(conts[b * 13 + lane]) : 0;
  if (lane < 752 - NPAIR) pw[NPAIR + lane] = 0;
  __syncthreads();

#pragma unroll
  for (int i = 0; i < 4; ++i) {
    int q = i * 64 + lane;
    if (q < 208)
      *(bf16x8*)&Xrow[16 + q * 8] =
          *(const bf16x8*)&my[(13 + (q >> 3)) * CCLD + (q & 7) * 8];
  }

  int r15 = lane & 15, hi = lane >> 4;
  bf16x8 fr[2][3];
#pragma unroll
  for (int t = 0; t < 3; ++t)
#pragma unroll
    for (int h = 0; h < 2; ++h)
      fr[h][t] = *(const bf16x8*)&my[(t * 16 + r15) * CCLD + h * 32 + hi * 8];

  f32x4 acc[3][3];
#pragma unroll
  for (int it = 0; it < 3; ++it)
#pragma unroll
    for (int jt = 0; jt < 3; ++jt)
      acc[it][jt] = (f32x4){0.f, 0.f, 0.f, 0.f};
#pragma unroll
  for (int h = 0; h < 2; ++h)
#pragma unroll
    for (int it = 0; it < 3; ++it)
#pragma unroll
      for (int jt = 0; jt < 3; ++jt)
        acc[it][jt] = __builtin_amdgcn_mfma_f32_16x16x32_bf16(
            fr[h][it], fr[h][jt], acc[it][jt], 0, 0, 0);

#pragma unroll
  for (int it = 0; it < 3; ++it)
#pragma unroll
    for (int jt = 0; jt < 3; ++jt) {
      int g = jt * 16 + r15;
#pragma unroll
      for (int r = 0; r < 4; ++r) {
        int f = it * 16 + hi * 4 + r;
        if (f < g && g < NF) {
          int p = f * 38 - ((f * (f - 1)) >> 1) + g - f - 1;
          pw[p] = f2bf(acc[it][jt][r]);
        }
      }
    }
  __syncthreads();

#pragma unroll
  for (int i = 0; i < 2; ++i) {
    int q = i * 64 + lane;
    if (q < 94)
      *(bf16x8*)&Xrow[1680 + q * 8] = *(const bf16x8*)&pw[q * 8];
  }
}

// ===================== shared GEMM machinery (r6 schedule) =====================
#define GLL(s_, d_) __builtin_amdgcn_global_load_lds((gptr_t)(s_), (lptr_t)(d_), 16, 0, 0)
#define RD(p_) (*(const bf16x8*)(p_))
#define DSTA(buf, h) (lds + (buf) * 32768 + (h) * 8192 + sd)
#define DSTB(buf, h) (lds + (buf) * 32768 + 16384 + (h) * 8192 + sd)
#define STG(dst, srcb, tau) do { \
    const unsigned short* _s = (srcb) + (size_t)(tau) * 64; \
    GLL(_s, dst); GLL(_s + (size_t)64 * K, (dst) + 4096); } while (0)
#define PHASE_BAR() do { \
    __builtin_amdgcn_s_barrier(); \
    asm volatile("s_waitcnt lgkmcnt(0)" ::: "memory"); \
    __builtin_amdgcn_sched_barrier(0); \
    __builtin_amdgcn_s_setprio(1); } while (0)
#define PHASE_END() do { \
    __builtin_amdgcn_s_setprio(0); \
    __builtin_amdgcn_s_barrier(); \
    __builtin_amdgcn_sched_barrier(0); } while (0)
#define MQ(I0, J0, AB, BB) do { \
    _Pragma("unroll") \
    for (int i_ = 0; i_ < 4; ++i_) \
      _Pragma("unroll") \
      for (int j_ = 0; j_ < 2; ++j_) { \
        acc[(I0) + i_][(J0) + j_] = __builtin_amdgcn_mfma_f32_16x16x32_bf16( \
            AB[i_][0], BB[j_][0], acc[(I0) + i_][(J0) + j_], 0, 0, 0); \
        acc[(I0) + i_][(J0) + j_] = __builtin_amdgcn_mfma_f32_16x16x32_bf16( \
            AB[i_][1], BB[j_][1], acc[(I0) + i_][(J0) + j_], 0, 0, 0); \
      } } while (0)

// ---- GEMM1: r6 loop verbatim; epilogue adds bias, bf16 store, AND per-(nb,wc) row stats
__global__ __launch_bounds__(512, 2) void gemm_8ph(
    const unsigned short* __restrict__ A, const unsigned short* __restrict__ Bt,
    const float* __restrict__ bias, unsigned short* __restrict__ Hout,
    float* __restrict__ stats, int K, int NT) {
  __shared__ unsigned short lds[65536];

  int bid = blockIdx.x;
  int swz = (bid & 7) * 32 + (bid >> 3);
  int mb = swz >> 2, nb = swz & 3;
  size_t m0 = (size_t)mb * 256, n0 = (size_t)nb * 256;

  int tid = threadIdx.x, lane = tid & 63, w = tid >> 6;
  int wr = w >> 2, wc = w & 3;
  int r15 = lane & 15, hi = lane >> 4;

  int sr = tid >> 3;
  int ce = ((tid & 7) ^ (sr & 7)) << 3;
  int sd = tid * 8;
  const unsigned short* A0p = A + (m0 + sr) * (size_t)K + ce;
  const unsigned short* A1p = A0p + (size_t)128 * K;
  const unsigned short* B0p = Bt + (n0 + sr) * (size_t)K + ce;
  const unsigned short* B1p = B0p + (size_t)128 * K;

  int cbs = (((hi << 4) ^ ((r15 & 7) << 4)) >> 1);
  int rb0 = r15 * 64 + cbs;
  int rb1 = rb0 ^ 32;
  const unsigned short* aH = lds + wr * 8192;
  const unsigned short* bH = lds + 16384 + (wc >> 1) * 8192 + (wc & 1) * 4096;

  f32x4 acc[8][4];
#pragma unroll
  for (int m = 0; m < 8; ++m)
#pragma unroll
    for (int n = 0; n < 4; ++n) acc[m][n] = (f32x4){0.f, 0.f, 0.f, 0.f};

  bf16x8 a0[4][2], a1[4][2], bS[2][2], bR[2][2];

  {
    int t1 = (NT > 1) ? 1 : 0;
    STG(DSTB(0, 0), B0p, 0);
    STG(DSTB(0, 1), B1p, 0);
    STG(DSTA(0, 0), A0p, 0);
    STG(DSTA(0, 1), A1p, 0);
    STG(DSTB(1, 0), B0p, t1);
    STG(DSTB(1, 1), B1p, t1);
    asm volatile("s_waitcnt vmcnt(4)" ::: "memory");
    __builtin_amdgcn_s_barrier();
    __builtin_amdgcn_sched_barrier(0);
#pragma unroll
    for (int i = 0; i < 4; ++i) {
      a0[i][0] = RD(aH + i * 1024 + rb0);
      a0[i][1] = RD(aH + i * 1024 + rb1);
    }
  }

  for (int t = 0; t < NT; ++t) {
    int cur = t & 1, nxt = cur ^ 1;
    int ta = (t + 1 < NT) ? t + 1 : NT - 1;
    int tb = (t + 2 < NT) ? t + 2 : NT - 1;
    const unsigned short* aBn = aH + nxt * 32768;
    const unsigned short* bB = bH + cur * 32768;

#pragma unroll
    for (int j = 0; j < 2; ++j) {
      bS[j][0] = RD(bB + j * 1024 + rb0);
      bS[j][1] = RD(bB + j * 1024 + rb1);
    }
    STG(DSTA(nxt, 0), A0p, ta);
    PHASE_BAR();
    MQ(0, 0, a0, bS);
    PHASE_END();

#pragma unroll
    for (int j = 0; j < 2; ++j) {
      bR[j][0] = RD(bB + (2 + j) * 1024 + rb0);
      bR[j][1] = RD(bB + (2 + j) * 1024 + rb1);
    }
#pragma unroll
    for (int i = 0; i < 4; ++i) {
      a1[i][0] = RD(aH + cur * 32768 + (4 + i) * 1024 + rb0);
      a1[i][1] = RD(aH + cur * 32768 + (4 + i) * 1024 + rb1);
    }
    STG(DSTA(nxt, 1), A1p, ta);
    __builtin_amdgcn_s_barrier();
    asm volatile("s_waitcnt lgkmcnt(8)" ::: "memory");
    __builtin_amdgcn_sched_barrier(0);
    __builtin_amdgcn_s_setprio(1);
    MQ(0, 2, a0, bR);
    PHASE_END();

    STG(DSTB(cur, 0), B0p, tb);
    PHASE_BAR();
    MQ(4, 2, a1, bR);
    PHASE_END();

    STG(DSTB(cur, 1), B1p, tb);
    asm volatile("s_waitcnt vmcnt(4)" ::: "memory");
    __builtin_amdgcn_s_barrier();
#pragma unroll
    for (int i = 0; i < 4; ++i) {
      a0[i][0] = RD(aBn + i * 1024 + rb0);
      a0[i][1] = RD(aBn + i * 1024 + rb1);
    }
    __builtin_amdgcn_sched_barrier(0);
    __builtin_amdgcn_s_setprio(1);
    MQ(4, 0, a1, bS);
    PHASE_END();
  }

  // epilogue: +bias, bf16 store, per-(nb,wc) row partial stats
  size_t crow = m0 + (size_t)wr * 128 + hi * 4;
  size_t ccol = n0 + (size_t)wc * 64 + r15;
  unsigned short* Hp = Hout + crow * NH + ccol;
  float bv[4];
#pragma unroll
  for (int n = 0; n < 4; ++n) bv[n] = bias[ccol + n * 16];
  float* sbase = stats + ((size_t)(nb * 4 + wc) * BATCH) * 2;
#pragma unroll
  for (int m = 0; m < 8; ++m) {
    float ps1[4] = {0.f, 0.f, 0.f, 0.f}, ps2[4] = {0.f, 0.f, 0.f, 0.f};
#pragma unroll
    for (int n = 0; n < 4; ++n)
#pragma unroll
      for (int q = 0; q < 4; ++q) {
        float v = acc[m][n][q] + bv[n];
        Hp[(size_t)(m * 16 + q) * NH + n * 16] = f2bf(v);
        ps1[q] += v;
        ps2[q] += v * v;
      }
#pragma unroll
    for (int q = 0; q < 4; ++q) {
      float t1 = ps1[q], t2 = ps2[q];
#pragma unroll
      for (int o = 1; o < 16; o <<= 1) {
        t1 += __shfl_xor(t1, o);
        t2 += __shfl_xor(t2, o);
      }
      if (r15 == 0) {
        size_t row = crow + m * 16 + q;
        float2* sp = (float2*)(sbase + row * 2);
        *sp = make_float2(t1, t2);
      }
    }
  }
}

// ---- GEMM2 fused with LN1+ReLU on the A operand (reg-staged A, GLL B)
__device__ __forceinline__ void transform8(uint4 p, float mu, float rs,
    const float* gv, const float* bb, unsigned short* o) {
  unsigned int wv[4] = {p.x, p.y, p.z, p.w};
  float nm = -mu * rs;
#pragma unroll
  for (int i = 0; i < 8; ++i) {
    unsigned short u = (i & 1) ? (unsigned short)(wv[i >> 1] >> 16)
                               : (unsigned short)(wv[i >> 1] & 0xffff);
    float v = bf2f(u);
    float x = fmaf(v, rs, nm);
    x = fmaxf(fmaf(x, gv[i], bb[i]), 0.f);
    o[i] = f2bf(x);
  }
}

__global__ __launch_bounds__(512, 2) void gemm2_fused(
    const unsigned short* __restrict__ Yb1, const unsigned short* __restrict__ Bt,
    const float* __restrict__ bias, const float* __restrict__ g1,
    const float* __restrict__ be1, const float* __restrict__ stats,
    unsigned short* __restrict__ Hout) {
  const int K = 1024, NT = 16;
  __shared__ unsigned short lds[65536];
  __shared__ float gbuf[2048];   // [0:1024) gamma, [1024:2048) beta
  __shared__ float sbuf[512];    // per-row (mu, rs)

  int bid = blockIdx.x;
  int swz = (bid & 7) * 32 + (bid >> 3);
  int mb = swz >> 2, nb = swz & 3;
  size_t m0 = (size_t)mb * 256, n0 = (size_t)nb * 256;

  int tid = threadIdx.x, lane = tid & 63, w = tid >> 6;
  int wr = w >> 2, wc = w & 3;
  int r15 = lane & 15, hi = lane >> 4;

  int sr = tid >> 3;
  int ce = ((tid & 7) ^ (sr & 7)) << 3;
  int sd = tid * 8;
  const unsigned short* B0p = Bt + (n0 + sr) * (size_t)K + ce;
  const unsigned short* B1p = B0p + (size_t)128 * K;
  const unsigned short* Arow0 = Yb1 + (m0 + sr) * (size_t)K + ce;         // rows sr / +64
  const unsigned short* Arow1 = Yb1 + (m0 + 128 + sr) * (size_t)K + ce;   // rows +128 / +192

  int cbs = (((hi << 4) ^ ((r15 & 7) << 4)) >> 1);
  int rb0 = r15 * 64 + cbs;
  int rb1 = rb0 ^ 32;
  const unsigned short* aH = lds + wr * 8192;
  const unsigned short* bH = lds + 16384 + (wc >> 1) * 8192 + (wc & 1) * 4096;

  f32x4 acc[8][4];
#pragma unroll
  for (int m = 0; m < 8; ++m)
#pragma unroll
    for (int n = 0; n < 4; ++n) acc[m][n] = (f32x4){0.f, 0.f, 0.f, 0.f};

  bf16x8 a0[4][2], a1[4][2], bS[2][2], bR[2][2];

  // ---- prologue part 1: gbuf/sbuf + B(0) staging
  {
    float2 gg = *(const float2*)&g1[tid * 2];
    gbuf[tid * 2] = gg.x; gbuf[tid * 2 + 1] = gg.y;
    float2 b2v = *(const float2*)&be1[tid * 2];
    gbuf[1024 + tid * 2] = b2v.x; gbuf[1024 + tid * 2 + 1] = b2v.y;
    if (tid < 256) {
      size_t row = m0 + tid;
      float s1 = 0.f, s2 = 0.f;
#pragma unroll
      for (int p = 0; p < 16; ++p) {
        float2 pp = *(const float2*)&stats[((size_t)p * BATCH + row) * 2];
        s1 += pp.x; s2 += pp.y;
      }
      float mu = s1 * (1.f / 1024.f);
      float var = s2 * (1.f / 1024.f) - mu * mu;
      sbuf[tid * 2] = mu;
      sbuf[tid * 2 + 1] = rsqrtf(var + 1e-5f);
    }
    STG(DSTB(0, 0), B0p, 0);
    STG(DSTB(0, 1), B1p, 0);
  }
  __syncthreads();

  // per-thread stats (rows sr, sr+64, sr+128, sr+192)
  float mu00 = sbuf[sr * 2],         rs00 = sbuf[sr * 2 + 1];
  float mu01 = sbuf[(sr + 64) * 2],  rs01 = sbuf[(sr + 64) * 2 + 1];
  float mu10 = sbuf[(sr + 128) * 2], rs10 = sbuf[(sr + 128) * 2 + 1];
  float mu11 = sbuf[(sr + 192) * 2], rs11 = sbuf[(sr + 192) * 2 + 1];

  float gv[8], bb[8];
  uint4 va, vb;
  unsigned short oa[8], ob[8];

  // ---- prologue part 2: fused-stage A(0), stage B(1)
  {
#pragma unroll
    for (int i = 0; i < 8; ++i) { gv[i] = gbuf[ce + i]; bb[i] = gbuf[1024 + ce + i]; }
    va = *(const uint4*)Arow0;
    vb = *(const uint4*)(Arow0 + (size_t)64 * K);
    transform8(va, mu00, rs00, gv, bb, oa);
    transform8(vb, mu01, rs01, gv, bb, ob);
    *(bf16x8*)(DSTA(0, 0)) = *(bf16x8*)oa;
    *(bf16x8*)(DSTA(0, 0) + 4096) = *(bf16x8*)ob;
    va = *(const uint4*)Arow1;
    vb = *(const uint4*)(Arow1 + (size_t)64 * K);
    transform8(va, mu10, rs10, gv, bb, oa);
    transform8(vb, mu11, rs11, gv, bb, ob);
    *(bf16x8*)(DSTA(0, 1)) = *(bf16x8*)oa;
    *(bf16x8*)(DSTA(0, 1) + 4096) = *(bf16x8*)ob;
    STG(DSTB(1, 0), B0p, 1);
    STG(DSTB(1, 1), B1p, 1);
    asm volatile("s_waitcnt vmcnt(4) lgkmcnt(0)" ::: "memory");
    __builtin_amdgcn_s_barrier();
    __builtin_amdgcn_sched_barrier(0);
#pragma unroll
    for (int i = 0; i < 4; ++i) {
      a0[i][0] = RD(aH + i * 1024 + rb0);
      a0[i][1] = RD(aH + i * 1024 + rb1);
    }
  }

  for (int t = 0; t < NT; ++t) {
    int cur = t & 1, nxt = cur ^ 1;
    int ta = (t + 1 < NT) ? t + 1 : NT - 1;
    int tb = (t + 2 < NT) ? t + 2 : NT - 1;
    const unsigned short* aBn = aH + nxt * 32768;
    const unsigned short* bB = bH + cur * 32768;

    // ph0: glA0(ta) early; gb for ta; rd bS; Q0; transform+write A-half0(ta)
    va = *(const uint4*)(Arow0 + (size_t)ta * 64);
    vb = *(const uint4*)(Arow0 + (size_t)ta * 64 + (size_t)64 * K);
#pragma unroll
    for (int i = 0; i < 8; ++i) {
      gv[i] = gbuf[ta * 64 + ce + i];
      bb[i] = gbuf[1024 + ta * 64 + ce + i];
    }
#pragma unroll
    for (int j = 0; j < 2; ++j) {
      bS[j][0] = RD(bB + j * 1024 + rb0);
      bS[j][1] = RD(bB + j * 1024 + rb1);
    }
    PHASE_BAR();
    MQ(0, 0, a0, bS);
    __builtin_amdgcn_s_setprio(0);
    __builtin_amdgcn_sched_barrier(0);
    transform8(va, mu00, rs00, gv, bb, oa);
    transform8(vb, mu01, rs01, gv, bb, ob);
    *(bf16x8*)(DSTA(nxt, 0)) = *(bf16x8*)oa;
    *(bf16x8*)(DSTA(nxt, 0) + 4096) = *(bf16x8*)ob;
    __builtin_amdgcn_s_barrier();
    __builtin_amdgcn_sched_barrier(0);

    // ph1: glA1(ta) early; rd bR + a1; counted lgkm(8) covers bR; Q1; transform+write A-half1(ta)
    va = *(const uint4*)(Arow1 + (size_t)ta * 64);
    vb = *(const uint4*)(Arow1 + (size_t)ta * 64 + (size_t)64 * K);
#pragma unroll
    for (int j = 0; j < 2; ++j) {
      bR[j][0] = RD(bB + (2 + j) * 1024 + rb0);
      bR[j][1] = RD(bB + (2 + j) * 1024 + rb1);
    }
#pragma unroll
    for (int i = 0; i < 4; ++i) {
      a1[i][0] = RD(aH + cur * 32768 + (4 + i) * 1024 + rb0);
      a1[i][1] = RD(aH + cur * 32768 + (4 + i) * 1024 + rb1);
    }
    __builtin_amdgcn_s_barrier();
    asm volatile("s_waitcnt lgkmcnt(8)" ::: "memory");
    __builtin_amdgcn_sched_barrier(0);
    __builtin_amdgcn_s_setprio(1);
    MQ(0, 2, a0, bR);
    __builtin_amdgcn_s_setprio(0);
    __builtin_amdgcn_sched_barrier(0);
    transform8(va, mu10, rs10, gv, bb, oa);
    transform8(vb, mu11, rs11, gv, bb, ob);
    *(bf16x8*)(DSTA(nxt, 1)) = *(bf16x8*)oa;
    *(bf16x8*)(DSTA(nxt, 1) + 4096) = *(bf16x8*)ob;
    __builtin_amdgcn_s_barrier();
    __builtin_amdgcn_sched_barrier(0);

    // ph2: STG B0(tb); Q2
    STG(DSTB(cur, 0), B0p, tb);
    PHASE_BAR();
    MQ(4, 2, a1, bR);
    PHASE_END();

    // ph3: STG B1(tb); vmcnt(4) guarantees B(t+1) landed; rd a0<=A(t+1); Q3
    STG(DSTB(cur, 1), B1p, tb);
    asm volatile("s_waitcnt vmcnt(4)" ::: "memory");
    __builtin_amdgcn_s_barrier();
#pragma unroll
    for (int i = 0; i < 4; ++i) {
      a0[i][0] = RD(aBn + i * 1024 + rb0);
      a0[i][1] = RD(aBn + i * 1024 + rb1);
    }
    __builtin_amdgcn_sched_barrier(0);
    __builtin_amdgcn_s_setprio(1);
    MQ(4, 0, a1, bS);
    PHASE_END();
  }

  // epilogue: +bias, bf16 store
  size_t crow = m0 + (size_t)wr * 128 + hi * 4;
  size_t ccol = n0 + (size_t)wc * 64 + r15;
  unsigned short* Hp = Hout + crow * NH + ccol;
  float bv[4];
#pragma unroll
  for (int n = 0; n < 4; ++n) bv[n] = bias[ccol + n * 16];
#pragma unroll
  for (int m = 0; m < 8; ++m)
#pragma unroll
    for (int n = 0; n < 4; ++n)
#pragma unroll
      for (int q = 0; q < 4; ++q)
        Hp[(size_t)(m * 16 + q) * NH + n * 16] = f2bf(acc[m][n][q] + bv[n]);
}

// ---- layernorm + relu + dot(Wout) + sigmoid, wave-per-row
__global__ __launch_bounds__(256) void ln_out_kernel(
    const unsigned short* __restrict__ Yb, const float* __restrict__ gamma,
    const float* __restrict__ beta, const float* __restrict__ Wout,
    const float* __restrict__ bout, float* __restrict__ out) {
  int wid = threadIdx.x >> 6, lane = threadIdx.x & 63;
  int b = (blockIdx.x << 2) | wid;
  const unsigned short* yrow = Yb + (size_t)b * NH + lane * 16;
  bf16x8 u0 = *(const bf16x8*)&yrow[0];
  bf16x8 u1 = *(const bf16x8*)&yrow[8];
  float v[16];
#pragma unroll
  for (int i = 0; i < 8; ++i) {
    v[i] = bf2f((unsigned short)u0[i]);
    v[8 + i] = bf2f((unsigned short)u1[i]);
  }
  float s1 = 0.f, s2 = 0.f;
#pragma unroll
  for (int i = 0; i < 16; ++i) { s1 += v[i]; s2 += v[i] * v[i]; }
#pragma unroll
  for (int i = 1; i < 64; i <<= 1) {
    s1 += __shfl_xor(s1, i);
    s2 += __shfl_xor(s2, i);
  }
  float mu = s1 * (1.0f / NH);
  float var = s2 * (1.0f / NH) - mu * mu;
  float rs = rsqrtf(var + 1e-5f);
  const float4* gp = (const float4*)(gamma + lane * 16);
  const float4* bp = (const float4*)(beta + lane * 16);
  const float4* wp = (const float4*)(Wout + lane * 16);
  float s = 0.f;
#pragma unroll
  for (int q = 0; q < 4; ++q) {
    float4 gg = gp[q], be = bp[q], wo = wp[q];
    s += fmaxf((v[q * 4 + 0] - mu) * rs * gg.x + be.x, 0.f) * wo.x;
    s += fmaxf((v[q * 4 + 1] - mu) * rs * gg.y + be.y, 0.f) * wo.y;
    s += fmaxf((v[q * 4 + 2] - mu) * rs * gg.z + be.z, 0.f) * wo.z;
    s += fmaxf((v[q * 4 + 3] - mu) * rs * gg.w + be.w, 0.f) * wo.w;
  }
#pragma unroll
  for (int i = 1; i < 64; i <<= 1) s += __shfl_xor(s, i);
  if (lane == 0) out[b] = 1.f / (1.f + expf(-(s + bout[0])));
}

extern "C" void kernel_launch(void* const* d_in, const int* in_sizes, int n_in,
                              void* d_out, int out_size, void* d_ws, size_t ws_size,
                              hipStream_t stream) {
  const float* conts = (const float*)d_in[0];
  const int* cates = (const int*)d_in[1];
  const float* emb  = (const float*)d_in[3];
  const float* W1   = (const float*)d_in[4];
  const float* b1   = (const float*)d_in[5];
  const float* ln1g = (const float*)d_in[6];
  const float* ln1b = (const float*)d_in[7];
  const float* W2   = (const float*)d_in[8];
  const float* b2   = (const float*)d_in[9];
  const float* ln2g = (const float*)d_in[10];
  const float* ln2b = (const float*)d_in[11];
  const float* Wout = (const float*)d_in[12];
  const float* bout = (const float*)d_in[13];
  float* out = (float*)d_out;

  unsigned short* X   = (unsigned short*)d_ws;            // BATCH * KX
  unsigned short* W1t = X + (size_t)BATCH * KX;           // NH * KX
  unsigned short* W2t = W1t + (size_t)NH * KX;            // NH * NH
  unsigned short* Yb1 = W2t + (size_t)NH * NH;            // BATCH * NH
  unsigned short* Yb2 = Yb1 + (size_t)BATCH * NH;         // BATCH * NH
  float* stats = (float*)(Yb2 + (size_t)BATCH * NH);      // 16 * BATCH * 2 f32

  hipLaunchKernelGGL(wprep_kernel, dim3(KX / 32 + NH / 32, NH / 32), dim3(256), 0, stream,
                     W1, W2, emb, W1t, W2t);
  hipLaunchKernelGGL(feature_kernel, dim3(BATCH / 4), dim3(256), 0, stream,
                     conts, cates, emb, X);
  hipLaunchKernelGGL(gemm_8ph, dim3(256), dim3(512), 0, stream,
                     X, W1t, b1, Yb1, stats, KX, KX / 64);
  hipLaunchKernelGGL(gemm2_fused, dim3(256), dim3(512), 0, stream,
                     Yb1, W2t, b2, ln1g, ln1b, stats, Yb2);
  hipLaunchKernelGGL(ln_out_kernel, dim3(BATCH / 4), dim3(256), 0, stream,
                     Yb2, ln2g, ln2b, Wout, bout, out);
}

// Round 9
// 176.085 us; speedup vs baseline: 1.2936x; 1.2936x over previous
//
#include <hip/hip_runtime.h>
#include <hip/hip_bf16.h>

#define BATCH 16384
#define NH 1024
#define NF 39
#define CCLD 72
#define KX 2432      // GEMM1 K: [0:13 conts][13:16 pad0][16:1680 cate flat][1680:2421 pairs][2421:2432 pad0]
#define NPAIR 741

typedef __attribute__((ext_vector_type(8))) short bf16x8;
typedef __attribute__((ext_vector_type(4))) float f32x4;

typedef const __attribute__((address_space(1))) unsigned int* gptr_t;
typedef __attribute__((address_space(3))) unsigned int* lptr_t;

__device__ __forceinline__ float bf2f(unsigned short u) {
  union { unsigned int i; float f; } c; c.i = ((unsigned int)u) << 16; return c.f;
}
__device__ __forceinline__ unsigned short f2bf(float f) {
  union { float f; unsigned int i; } c; c.f = f;
  unsigned int r = c.i + 0x7FFFu + ((c.i >> 16) & 1u);
  return (unsigned short)(r >> 16);
}

// ---- merged W-prep: blocks [0,76) build W1t (row-remapped, M13 inline), [76,108) build W2t
__global__ __launch_bounds__(256) void wprep_kernel(
    const float* __restrict__ W1, const float* __restrict__ W2,
    const float* __restrict__ emb, unsigned short* __restrict__ W1t,
    unsigned short* __restrict__ W2t) {
  __shared__ float tile[32][33];
  int bx = blockIdx.x;
  int nb = blockIdx.y * 32;
  int tx = threadIdx.x & 31, ty = threadIdx.x >> 5;
  if (bx < KX / 32) {
    int kb = bx * 32;
#pragma unroll
    for (int i = 0; i < 32; i += 8) {
      int k = kb + ty + i;
      float v = 0.f;
      if (k < 13) {
        float s = 0.f;
#pragma unroll 8
        for (int d = 0; d < 64; ++d)
          s += emb[k * 64 + d] * W1[(size_t)(k * 64 + d) * NH + nb + tx];
        v = s;
      } else if (k >= 16 && k < 1680) {
        v = W1[(size_t)(832 + k - 16) * NH + nb + tx];
      } else if (k >= 1680 && k < 1680 + NPAIR) {
        v = W1[(size_t)(2496 + k - 1680) * NH + nb + tx];
      }
      tile[ty + i][tx] = v;
    }
    __syncthreads();
#pragma unroll
    for (int i = 0; i < 32; i += 8)
      W1t[(size_t)(nb + ty + i) * KX + kb + tx] = f2bf(tile[tx][ty + i]);
  } else {
    int kb = (bx - KX / 32) * 32;
#pragma unroll
    for (int i = 0; i < 32; i += 8)
      tile[ty + i][tx] = W2[(size_t)(kb + ty + i) * NH + nb + tx];
    __syncthreads();
#pragma unroll
    for (int i = 0; i < 32; i += 8)
      W2t[(size_t)(nb + ty + i) * NH + kb + tx] = f2bf(tile[tx][ty + i]);
  }
}

// ---- features -> X' rows: [conts 13 | 0 | cate flat 1664 | pairs 741 | 0]
// Gather section restructured for ILP: all index loads first, then all 26 emb
// gathers issued as independent loads (dep chain 26 -> 2), then converts.
__global__ __launch_bounds__(256) void feature_kernel(
    const float* __restrict__ conts, const int* __restrict__ cates,
    const float* __restrict__ emb, unsigned short* __restrict__ X) {
  __shared__ unsigned short cc[4][48 * CCLD];
  __shared__ unsigned short pb[4][752];
  int wid = threadIdx.x >> 6, lane = threadIdx.x & 63;
  int b = (blockIdx.x << 2) | wid;
  unsigned short* my = cc[wid];
  unsigned short* pw = pb[wid];
  unsigned short* Xrow = X + (size_t)b * KX;

  // 1) all cate indices (26 ints = 13 aligned int2) + all conts, issued up front
  int2 c2[13];
#pragma unroll
  for (int i = 0; i < 13; ++i)
    c2[i] = ((const int2*)(cates + b * 26))[i];
  float cf[13];
#pragma unroll
  for (int f = 0; f < 13; ++f) cf[f] = conts[b * 13 + f];
  // 2) cont emb rows (fixed rows 0..12, L1-hot) — independent
  float cemb[13];
#pragma unroll
  for (int f = 0; f < 13; ++f) cemb[f] = emb[f * 64 + lane];
  // 3) all 26 gathers issued back-to-back (only dep: its own index load)
  float g[26];
#pragma unroll
  for (int j = 0; j < 26; ++j) {
    int idx = (j & 1) ? c2[j >> 1].y : c2[j >> 1].x;
    g[j] = emb[(size_t)idx * 64 + lane];
  }
  // 4) convert + stage to LDS
#pragma unroll
  for (int f = 0; f < 13; ++f)
    my[f * CCLD + lane] = f2bf(cemb[f] * cf[f]);
#pragma unroll
  for (int j = 0; j < 26; ++j)
    my[(13 + j) * CCLD + lane] = f2bf(g[j]);
#pragma unroll
  for (int f = NF; f < 48; ++f) my[f * CCLD + lane] = 0;
  if (lane < 16) Xrow[lane] = (lane < 13) ? f2bf(cf[lane]) : 0;
  if (lane < 752 - NPAIR) pw[NPAIR + lane] = 0;
  __syncthreads();

  // cate flat: 1664 shorts = 208 x bf16x8
#pragma unroll
  for (int i = 0; i < 4; ++i) {
    int q = i * 64 + lane;
    if (q < 208)
      *(bf16x8*)&Xrow[16 + q * 8] =
          *(const bf16x8*)&my[(13 + (q >> 3)) * CCLD + (q & 7) * 8];
  }

  // gram via MFMA (frag is both A and B operand)
  int r15 = lane & 15, hi = lane >> 4;
  bf16x8 fr[2][3];
#pragma unroll
  for (int t = 0; t < 3; ++t)
#pragma unroll
    for (int h = 0; h < 2; ++h)
      fr[h][t] = *(const bf16x8*)&my[(t * 16 + r15) * CCLD + h * 32 + hi * 8];

  f32x4 acc[3][3];
#pragma unroll
  for (int it = 0; it < 3; ++it)
#pragma unroll
    for (int jt = 0; jt < 3; ++jt)
      acc[it][jt] = (f32x4){0.f, 0.f, 0.f, 0.f};
#pragma unroll
  for (int h = 0; h < 2; ++h)
#pragma unroll
    for (int it = 0; it < 3; ++it)
#pragma unroll
      for (int jt = 0; jt < 3; ++jt)
        acc[it][jt] = __builtin_amdgcn_mfma_f32_16x16x32_bf16(
            fr[h][it], fr[h][jt], acc[it][jt], 0, 0, 0);

#pragma unroll
  for (int it = 0; it < 3; ++it)
#pragma unroll
    for (int jt = 0; jt < 3; ++jt) {
      int g_ = jt * 16 + r15;
#pragma unroll
      for (int r = 0; r < 4; ++r) {
        int f = it * 16 + hi * 4 + r;
        if (f < g_ && g_ < NF) {
          int p = f * 38 - ((f * (f - 1)) >> 1) + g_ - f - 1;
          pw[p] = f2bf(acc[it][jt][r]);
        }
      }
    }
  __syncthreads();

#pragma unroll
  for (int i = 0; i < 2; ++i) {
    int q = i * 64 + lane;
    if (q < 94)
      *(bf16x8*)&Xrow[1680 + q * 8] = *(const bf16x8*)&pw[q * 8];
  }
}

// ============ 256x256 GEMM: r6 schedule verbatim ============
#define GLL(s_, d_) __builtin_amdgcn_global_load_lds((gptr_t)(s_), (lptr_t)(d_), 16, 0, 0)
#define RD(p_) (*(const bf16x8*)(p_))
#define DSTA(buf, h) (lds + (buf) * 32768 + (h) * 8192 + sd)
#define DSTB(buf, h) (lds + (buf) * 32768 + 16384 + (h) * 8192 + sd)
#define STG(dst, srcb, tau) do { \
    const unsigned short* _s = (srcb) + (size_t)(tau) * 64; \
    GLL(_s, dst); GLL(_s + (size_t)64 * K, (dst) + 4096); } while (0)
#define PHASE_BAR() do { \
    __builtin_amdgcn_s_barrier(); \
    asm volatile("s_waitcnt lgkmcnt(0)" ::: "memory"); \
    __builtin_amdgcn_sched_barrier(0); \
    __builtin_amdgcn_s_setprio(1); } while (0)
#define PHASE_END() do { \
    __builtin_amdgcn_s_setprio(0); \
    __builtin_amdgcn_s_barrier(); \
    __builtin_amdgcn_sched_barrier(0); } while (0)
#define MQ(I0, J0, AB, BB) do { \
    _Pragma("unroll") \
    for (int i_ = 0; i_ < 4; ++i_) \
      _Pragma("unroll") \
      for (int j_ = 0; j_ < 2; ++j_) { \
        acc[(I0) + i_][(J0) + j_] = __builtin_amdgcn_mfma_f32_16x16x32_bf16( \
            AB[i_][0], BB[j_][0], acc[(I0) + i_][(J0) + j_], 0, 0, 0); \
        acc[(I0) + i_][(J0) + j_] = __builtin_amdgcn_mfma_f32_16x16x32_bf16( \
            AB[i_][1], BB[j_][1], acc[(I0) + i_][(J0) + j_], 0, 0, 0); \
      } } while (0)

__global__ __launch_bounds__(512, 2) void gemm_8ph(
    const unsigned short* __restrict__ A, const unsigned short* __restrict__ Bt,
    const float* __restrict__ bias, unsigned short* __restrict__ Hout,
    int K, int NT) {
  __shared__ unsigned short lds[65536];

  int bid = blockIdx.x;
  int swz = (bid & 7) * 32 + (bid >> 3);
  int mb = swz >> 2, nb = swz & 3;
  size_t m0 = (size_t)mb * 256, n0 = (size_t)nb * 256;

  int tid = threadIdx.x, lane = tid & 63, w = tid >> 6;
  int wr = w >> 2, wc = w & 3;
  int r15 = lane & 15, hi = lane >> 4;

  int sr = tid >> 3;
  int ce = ((tid & 7) ^ (sr & 7)) << 3;
  int sd = tid * 8;
  const unsigned short* A0p = A + (m0 + sr) * (size_t)K + ce;
  const unsigned short* A1p = A0p + (size_t)128 * K;
  const unsigned short* B0p = Bt + (n0 + sr) * (size_t)K + ce;
  const unsigned short* B1p = B0p + (size_t)128 * K;

  int cbs = (((hi << 4) ^ ((r15 & 7) << 4)) >> 1);
  int rb0 = r15 * 64 + cbs;
  int rb1 = rb0 ^ 32;
  const unsigned short* aH = lds + wr * 8192;
  const unsigned short* bH = lds + 16384 + (wc >> 1) * 8192 + (wc & 1) * 4096;

  f32x4 acc[8][4];
#pragma unroll
  for (int m = 0; m < 8; ++m)
#pragma unroll
    for (int n = 0; n < 4; ++n) acc[m][n] = (f32x4){0.f, 0.f, 0.f, 0.f};

  bf16x8 a0[4][2], a1[4][2], bS[2][2], bR[2][2];

  {
    int t1 = (NT > 1) ? 1 : 0;
    STG(DSTB(0, 0), B0p, 0);
    STG(DSTB(0, 1), B1p, 0);
    STG(DSTA(0, 0), A0p, 0);
    STG(DSTA(0, 1), A1p, 0);
    STG(DSTB(1, 0), B0p, t1);
    STG(DSTB(1, 1), B1p, t1);
    asm volatile("s_waitcnt vmcnt(4)" ::: "memory");
    __builtin_amdgcn_s_barrier();
    __builtin_amdgcn_sched_barrier(0);
#pragma unroll
    for (int i = 0; i < 4; ++i) {
      a0[i][0] = RD(aH + i * 1024 + rb0);
      a0[i][1] = RD(aH + i * 1024 + rb1);
    }
  }

  for (int t = 0; t < NT; ++t) {
    int cur = t & 1, nxt = cur ^ 1;
    int ta = (t + 1 < NT) ? t + 1 : NT - 1;
    int tb = (t + 2 < NT) ? t + 2 : NT - 1;
    const unsigned short* aBn = aH + nxt * 32768;
    const unsigned short* bB = bH + cur * 32768;

#pragma unroll
    for (int j = 0; j < 2; ++j) {
      bS[j][0] = RD(bB + j * 1024 + rb0);
      bS[j][1] = RD(bB + j * 1024 + rb1);
    }
    STG(DSTA(nxt, 0), A0p, ta);
    PHASE_BAR();
    MQ(0, 0, a0, bS);
    PHASE_END();

#pragma unroll
    for (int j = 0; j < 2; ++j) {
      bR[j][0] = RD(bB + (2 + j) * 1024 + rb0);
      bR[j][1] = RD(bB + (2 + j) * 1024 + rb1);
    }
#pragma unroll
    for (int i = 0; i < 4; ++i) {
      a1[i][0] = RD(aH + cur * 32768 + (4 + i) * 1024 + rb0);
      a1[i][1] = RD(aH + cur * 32768 + (4 + i) * 1024 + rb1);
    }
    STG(DSTA(nxt, 1), A1p, ta);
    __builtin_amdgcn_s_barrier();
    asm volatile("s_waitcnt lgkmcnt(8)" ::: "memory");
    __builtin_amdgcn_sched_barrier(0);
    __builtin_amdgcn_s_setprio(1);
    MQ(0, 2, a0, bR);
    PHASE_END();

    STG(DSTB(cur, 0), B0p, tb);
    PHASE_BAR();
    MQ(4, 2, a1, bR);
    PHASE_END();

    STG(DSTB(cur, 1), B1p, tb);
    asm volatile("s_waitcnt vmcnt(4)" ::: "memory");
    __builtin_amdgcn_s_barrier();
#pragma unroll
    for (int i = 0; i < 4; ++i) {
      a0[i][0] = RD(aBn + i * 1024 + rb0);
      a0[i][1] = RD(aBn + i * 1024 + rb1);
    }
    __builtin_amdgcn_sched_barrier(0);
    __builtin_amdgcn_s_setprio(1);
    MQ(4, 0, a1, bS);
    PHASE_END();
  }

  // epilogue: +bias, bf16 store. C/D: col=lane&15, row=(lane>>4)*4+q
  size_t crow = m0 + (size_t)wr * 128 + hi * 4;
  size_t ccol = n0 + (size_t)wc * 64 + r15;
  unsigned short* Hp = Hout + crow * NH + ccol;
  float bv[4];
#pragma unroll
  for (int n = 0; n < 4; ++n) bv[n] = bias[ccol + n * 16];
#pragma unroll
  for (int m = 0; m < 8; ++m)
#pragma unroll
    for (int n = 0; n < 4; ++n)
#pragma unroll
      for (int q = 0; q < 4; ++q)
        Hp[(size_t)(m * 16 + q) * NH + n * 16] = f2bf(acc[m][n][q] + bv[n]);
}

// ---- layernorm + relu, wave-per-row (16 elems/lane), no LDS / no block sync
__global__ __launch_bounds__(256) void ln_relu_kernel(
    const unsigned short* __restrict__ Yb, const float* __restrict__ gamma,
    const float* __restrict__ beta, unsigned short* __restrict__ H) {
  int wid = threadIdx.x >> 6, lane = threadIdx.x & 63;
  int b = (blockIdx.x << 2) | wid;
  const unsigned short* yrow = Yb + (size_t)b * NH + lane * 16;
  bf16x8 u0 = *(const bf16x8*)&yrow[0];
  bf16x8 u1 = *(const bf16x8*)&yrow[8];
  float v[16];
#pragma unroll
  for (int i = 0; i < 8; ++i) {
    v[i] = bf2f((unsigned short)u0[i]);
    v[8 + i] = bf2f((unsigned short)u1[i]);
  }
  float s1 = 0.f, s2 = 0.f;
#pragma unroll
  for (int i = 0; i < 16; ++i) { s1 += v[i]; s2 += v[i] * v[i]; }
#pragma unroll
  for (int i = 1; i < 64; i <<= 1) {
    s1 += __shfl_xor(s1, i);
    s2 += __shfl_xor(s2, i);
  }
  float mu = s1 * (1.0f / NH);
  float var = s2 * (1.0f / NH) - mu * mu;
  float rs = rsqrtf(var + 1e-5f);
  const float4* gp = (const float4*)(gamma + lane * 16);
  const float4* bp = (const float4*)(beta + lane * 16);
  unsigned short o[16];
#pragma unroll
  for (int q = 0; q < 4; ++q) {
    float4 gg = gp[q], be = bp[q];
    o[q * 4 + 0] = f2bf(fmaxf((v[q * 4 + 0] - mu) * rs * gg.x + be.x, 0.f));
    o[q * 4 + 1] = f2bf(fmaxf((v[q * 4 + 1] - mu) * rs * gg.y + be.y, 0.f));
    o[q * 4 + 2] = f2bf(fmaxf((v[q * 4 + 2] - mu) * rs * gg.z + be.z, 0.f));
    o[q * 4 + 3] = f2bf(fmaxf((v[q * 4 + 3] - mu) * rs * gg.w + be.w, 0.f));
  }
  unsigned short* hrow = H + (size_t)b * NH + lane * 16;
  *(ulonglong2*)&hrow[0] = *(const ulonglong2*)&o[0];
  *(ulonglong2*)&hrow[8] = *(const ulonglong2*)&o[8];
}

// ---- layernorm + relu + dot(Wout) + sigmoid, wave-per-row
__global__ __launch_bounds__(256) void ln_out_kernel(
    const unsigned short* __restrict__ Yb, const float* __restrict__ gamma,
    const float* __restrict__ beta, const float* __restrict__ Wout,
    const float* __restrict__ bout, float* __restrict__ out) {
  int wid = threadIdx.x >> 6, lane = threadIdx.x & 63;
  int b = (blockIdx.x << 2) | wid;
  const unsigned short* yrow = Yb + (size_t)b * NH + lane * 16;
  bf16x8 u0 = *(const bf16x8*)&yrow[0];
  bf16x8 u1 = *(const bf16x8*)&yrow[8];
  float v[16];
#pragma unroll
  for (int i = 0; i < 8; ++i) {
    v[i] = bf2f((unsigned short)u0[i]);
    v[8 + i] = bf2f((unsigned short)u1[i]);
  }
  float s1 = 0.f, s2 = 0.f;
#pragma unroll
  for (int i = 0; i < 16; ++i) { s1 += v[i]; s2 += v[i] * v[i]; }
#pragma unroll
  for (int i = 1; i < 64; i <<= 1) {
    s1 += __shfl_xor(s1, i);
    s2 += __shfl_xor(s2, i);
  }
  float mu = s1 * (1.0f / NH);
  float var = s2 * (1.0f / NH) - mu * mu;
  float rs = rsqrtf(var + 1e-5f);
  const float4* gp = (const float4*)(gamma + lane * 16);
  const float4* bp = (const float4*)(beta + lane * 16);
  const float4* wp = (const float4*)(Wout + lane * 16);
  float s = 0.f;
#pragma unroll
  for (int q = 0; q < 4; ++q) {
    float4 gg = gp[q], be = bp[q], wo = wp[q];
    s += fmaxf((v[q * 4 + 0] - mu) * rs * gg.x + be.x, 0.f) * wo.x;
    s += fmaxf((v[q * 4 + 1] - mu) * rs * gg.y + be.y, 0.f) * wo.y;
    s += fmaxf((v[q * 4 + 2] - mu) * rs * gg.z + be.z, 0.f) * wo.z;
    s += fmaxf((v[q * 4 + 3] - mu) * rs * gg.w + be.w, 0.f) * wo.w;
  }
#pragma unroll
  for (int i = 1; i < 64; i <<= 1) s += __shfl_xor(s, i);
  if (lane == 0) out[b] = 1.f / (1.f + expf(-(s + bout[0])));
}

extern "C" void kernel_launch(void* const* d_in, const int* in_sizes, int n_in,
                              void* d_out, int out_size, void* d_ws, size_t ws_size,
                              hipStream_t stream) {
  const float* conts = (const float*)d_in[0];
  const int* cates = (const int*)d_in[1];
  const float* emb  = (const float*)d_in[3];
  const float* W1   = (const float*)d_in[4];
  const float* b1   = (const float*)d_in[5];
  const float* ln1g = (const float*)d_in[6];
  const float* ln1b = (const float*)d_in[7];
  const float* W2   = (const float*)d_in[8];
  const float* b2   = (const float*)d_in[9];
  const float* ln2g = (const float*)d_in[10];
  const float* ln2b = (const float*)d_in[11];
  const float* Wout = (const float*)d_in[12];
  const float* bout = (const float*)d_in[13];
  float* out = (float*)d_out;

  unsigned short* X   = (unsigned short*)d_ws;            // BATCH * KX
  unsigned short* W1t = X + (size_t)BATCH * KX;           // NH * KX
  unsigned short* W2t = W1t + (size_t)NH * KX;            // NH * NH
  unsigned short* H1  = W2t + (size_t)NH * NH;            // BATCH * NH
  unsigned short* Yb1 = H1 + (size_t)BATCH * NH;          // BATCH * NH
  unsigned short* Yb2 = Yb1 + (size_t)BATCH * NH;         // BATCH * NH

  hipLaunchKernelGGL(wprep_kernel, dim3(KX / 32 + NH / 32, NH / 32), dim3(256), 0, stream,
                     W1, W2, emb, W1t, W2t);
  hipLaunchKernelGGL(feature_kernel, dim3(BATCH / 4), dim3(256), 0, stream,
                     conts, cates, emb, X);
  hipLaunchKernelGGL(gemm_8ph, dim3(256), dim3(512), 0, stream,
                     X, W1t, b1, Yb1, KX, KX / 64);
  hipLaunchKernelGGL(ln_relu_kernel, dim3(BATCH / 4), dim3(256), 0, stream,
                     Yb1, ln1g, ln1b, H1);
  hipLaunchKernelGGL(gemm_8ph, dim3(256), dim3(512), 0, stream,
                     H1, W2t, b2, Yb2, NH, NH / 64);
  hipLaunchKernelGGL(ln_out_kernel, dim3(BATCH / 4), dim3(256), 0, stream,
                     Yb2, ln2g, ln2b, Wout, bout, out);
}

// Round 10
// 171.061 us; speedup vs baseline: 1.3316x; 1.0294x over previous
//
#include <hip/hip_runtime.h>
#include <hip/hip_bf16.h>

#define BATCH 16384
#define NH 1024
#define NF 39
#define CCLD 72
#define KX 2432      // GEMM1 K: [0:13 conts][13:16 pad0][16:1680 cate flat][1680:2421 pairs][2421:2432 pad0]
#define NPAIR 741
#define FEAT_BLOCKS (BATCH / 4)           // 4096
#define WPREP_BX (KX / 32 + NH / 32)      // 108
#define WPREP_BLOCKS (WPREP_BX * (NH / 32))  // 3456

typedef __attribute__((ext_vector_type(8))) short bf16x8;
typedef __attribute__((ext_vector_type(4))) float f32x4;

typedef const __attribute__((address_space(1))) unsigned int* gptr_t;
typedef __attribute__((address_space(3))) unsigned int* lptr_t;

__device__ __forceinline__ float bf2f(unsigned short u) {
  union { unsigned int i; float f; } c; c.i = ((unsigned int)u) << 16; return c.f;
}
__device__ __forceinline__ unsigned short f2bf(float f) {
  union { float f; unsigned int i; } c; c.f = f;
  unsigned int r = c.i + 0x7FFFu + ((c.i >> 16) & 1u);
  return (unsigned short)(r >> 16);
}

// ===== merged prep: blocks [0,4096) = features; [4096, 7552) = W1t/W2t build =====
// Bodies identical to r9's feature_kernel / wprep_kernel; LDS aliased.
__global__ __launch_bounds__(256) void prep_kernel(
    const float* __restrict__ conts, const int* __restrict__ cates,
    const float* __restrict__ emb, unsigned short* __restrict__ X,
    const float* __restrict__ W1, const float* __restrict__ W2,
    unsigned short* __restrict__ W1t, unsigned short* __restrict__ W2t) {
  __shared__ __align__(16) unsigned char smem[33664];

  if (blockIdx.x >= FEAT_BLOCKS) {
    // ---------------- W-prep path ----------------
    int wq = blockIdx.x - FEAT_BLOCKS;
    int bx = wq % WPREP_BX;
    int nb = (wq / WPREP_BX) * 32;
    float (*tile)[33] = (float(*)[33])smem;
    int tx = threadIdx.x & 31, ty = threadIdx.x >> 5;
    if (bx < KX / 32) {
      int kb = bx * 32;
#pragma unroll
      for (int i = 0; i < 32; i += 8) {
        int k = kb + ty + i;
        float v = 0.f;
        if (k < 13) {
          float s = 0.f;
#pragma unroll 8
          for (int d = 0; d < 64; ++d)
            s += emb[k * 64 + d] * W1[(size_t)(k * 64 + d) * NH + nb + tx];
          v = s;
        } else if (k >= 16 && k < 1680) {
          v = W1[(size_t)(832 + k - 16) * NH + nb + tx];
        } else if (k >= 1680 && k < 1680 + NPAIR) {
          v = W1[(size_t)(2496 + k - 1680) * NH + nb + tx];
        }
        tile[ty + i][tx] = v;
      }
      __syncthreads();
#pragma unroll
      for (int i = 0; i < 32; i += 8)
        W1t[(size_t)(nb + ty + i) * KX + kb + tx] = f2bf(tile[tx][ty + i]);
    } else {
      int kb = (bx - KX / 32) * 32;
#pragma unroll
      for (int i = 0; i < 32; i += 8)
        tile[ty + i][tx] = W2[(size_t)(kb + ty + i) * NH + nb + tx];
      __syncthreads();
#pragma unroll
      for (int i = 0; i < 32; i += 8)
        W2t[(size_t)(nb + ty + i) * NH + kb + tx] = f2bf(tile[tx][ty + i]);
    }
    return;
  }

  // ---------------- feature path ----------------
  int wid = threadIdx.x >> 6, lane = threadIdx.x & 63;
  int b = (blockIdx.x << 2) | wid;
  unsigned short* my = (unsigned short*)smem + wid * (48 * CCLD);
  unsigned short* pw = (unsigned short*)(smem + 27648) + wid * 752;
  unsigned short* Xrow = X + (size_t)b * KX;

  int2 c2[13];
#pragma unroll
  for (int i = 0; i < 13; ++i)
    c2[i] = ((const int2*)(cates + b * 26))[i];
  float cf[13];
#pragma unroll
  for (int f = 0; f < 13; ++f) cf[f] = conts[b * 13 + f];
  float cemb[13];
#pragma unroll
  for (int f = 0; f < 13; ++f) cemb[f] = emb[f * 64 + lane];
  float g[26];
#pragma unroll
  for (int j = 0; j < 26; ++j) {
    int idx = (j & 1) ? c2[j >> 1].y : c2[j >> 1].x;
    g[j] = emb[(size_t)idx * 64 + lane];
  }
#pragma unroll
  for (int f = 0; f < 13; ++f)
    my[f * CCLD + lane] = f2bf(cemb[f] * cf[f]);
#pragma unroll
  for (int j = 0; j < 26; ++j)
    my[(13 + j) * CCLD + lane] = f2bf(g[j]);
#pragma unroll
  for (int f = NF; f < 48; ++f) my[f * CCLD + lane] = 0;
  if (lane < 16) Xrow[lane] = (lane < 13) ? f2bf(cf[lane]) : 0;
  if (lane < 752 - NPAIR) pw[NPAIR + lane] = 0;
  __syncthreads();

#pragma unroll
  for (int i = 0; i < 4; ++i) {
    int q = i * 64 + lane;
    if (q < 208)
      *(bf16x8*)&Xrow[16 + q * 8] =
          *(const bf16x8*)&my[(13 + (q >> 3)) * CCLD + (q & 7) * 8];
  }

  int r15 = lane & 15, hi = lane >> 4;
  bf16x8 fr[2][3];
#pragma unroll
  for (int t = 0; t < 3; ++t)
#pragma unroll
    for (int h = 0; h < 2; ++h)
      fr[h][t] = *(const bf16x8*)&my[(t * 16 + r15) * CCLD + h * 32 + hi * 8];

  f32x4 acc[3][3];
#pragma unroll
  for (int it = 0; it < 3; ++it)
#pragma unroll
    for (int jt = 0; jt < 3; ++jt)
      acc[it][jt] = (f32x4){0.f, 0.f, 0.f, 0.f};
#pragma unroll
  for (int h = 0; h < 2; ++h)
#pragma unroll
    for (int it = 0; it < 3; ++it)
#pragma unroll
      for (int jt = 0; jt < 3; ++jt)
        acc[it][jt] = __builtin_amdgcn_mfma_f32_16x16x32_bf16(
            fr[h][it], fr[h][jt], acc[it][jt], 0, 0, 0);

#pragma unroll
  for (int it = 0; it < 3; ++it)
#pragma unroll
    for (int jt = 0; jt < 3; ++jt) {
      int g_ = jt * 16 + r15;
#pragma unroll
      for (int r = 0; r < 4; ++r) {
        int f = it * 16 + hi * 4 + r;
        if (f < g_ && g_ < NF) {
          int p = f * 38 - ((f * (f - 1)) >> 1) + g_ - f - 1;
          pw[p] = f2bf(acc[it][jt][r]);
        }
      }
    }
  __syncthreads();

#pragma unroll
  for (int i = 0; i < 2; ++i) {
    int q = i * 64 + lane;
    if (q < 94)
      *(bf16x8*)&Xrow[1680 + q * 8] = *(const bf16x8*)&pw[q * 8];
  }
}

// ============ 256x256 GEMM: r6 schedule verbatim ============
#define GLL(s_, d_) __builtin_amdgcn_global_load_lds((gptr_t)(s_), (lptr_t)(d_), 16, 0, 0)
#define RD(p_) (*(const bf16x8*)(p_))
#define DSTA(buf, h) (lds + (buf) * 32768 + (h) * 8192 + sd)
#define DSTB(buf, h) (lds + (buf) * 32768 + 16384 + (h) * 8192 + sd)
#define STG(dst, srcb, tau) do { \
    const unsigned short* _s = (srcb) + (size_t)(tau) * 64; \
    GLL(_s, dst); GLL(_s + (size_t)64 * K, (dst) + 4096); } while (0)
#define PHASE_BAR() do { \
    __builtin_amdgcn_s_barrier(); \
    asm volatile("s_waitcnt lgkmcnt(0)" ::: "memory"); \
    __builtin_amdgcn_sched_barrier(0); \
    __builtin_amdgcn_s_setprio(1); } while (0)
#define PHASE_END() do { \
    __builtin_amdgcn_s_setprio(0); \
    __builtin_amdgcn_s_barrier(); \
    __builtin_amdgcn_sched_barrier(0); } while (0)
#define MQ(I0, J0, AB, BB) do { \
    _Pragma("unroll") \
    for (int i_ = 0; i_ < 4; ++i_) \
      _Pragma("unroll") \
      for (int j_ = 0; j_ < 2; ++j_) { \
        acc[(I0) + i_][(J0) + j_] = __builtin_amdgcn_mfma_f32_16x16x32_bf16( \
            AB[i_][0], BB[j_][0], acc[(I0) + i_][(J0) + j_], 0, 0, 0); \
        acc[(I0) + i_][(J0) + j_] = __builtin_amdgcn_mfma_f32_16x16x32_bf16( \
            AB[i_][1], BB[j_][1], acc[(I0) + i_][(J0) + j_], 0, 0, 0); \
      } } while (0)

__global__ __launch_bounds__(512, 2) void gemm_8ph(
    const unsigned short* __restrict__ A, const unsigned short* __restrict__ Bt,
    const float* __restrict__ bias, unsigned short* __restrict__ Hout,
    int K, int NT) {
  __shared__ unsigned short lds[65536];

  int bid = blockIdx.x;
  int swz = (bid & 7) * 32 + (bid >> 3);
  int mb = swz >> 2, nb = swz & 3;
  size_t m0 = (size_t)mb * 256, n0 = (size_t)nb * 256;

  int tid = threadIdx.x, lane = tid & 63, w = tid >> 6;
  int wr = w >> 2, wc = w & 3;
  int r15 = lane & 15, hi = lane >> 4;

  int sr = tid >> 3;
  int ce = ((tid & 7) ^ (sr & 7)) << 3;
  int sd = tid * 8;
  const unsigned short* A0p = A + (m0 + sr) * (size_t)K + ce;
  const unsigned short* A1p = A0p + (size_t)128 * K;
  const unsigned short* B0p = Bt + (n0 + sr) * (size_t)K + ce;
  const unsigned short* B1p = B0p + (size_t)128 * K;

  int cbs = (((hi << 4) ^ ((r15 & 7) << 4)) >> 1);
  int rb0 = r15 * 64 + cbs;
  int rb1 = rb0 ^ 32;
  const unsigned short* aH = lds + wr * 8192;
  const unsigned short* bH = lds + 16384 + (wc >> 1) * 8192 + (wc & 1) * 4096;

  f32x4 acc[8][4];
#pragma unroll
  for (int m = 0; m < 8; ++m)
#pragma unroll
    for (int n = 0; n < 4; ++n) acc[m][n] = (f32x4){0.f, 0.f, 0.f, 0.f};

  bf16x8 a0[4][2], a1[4][2], bS[2][2], bR[2][2];

  {
    int t1 = (NT > 1) ? 1 : 0;
    STG(DSTB(0, 0), B0p, 0);
    STG(DSTB(0, 1), B1p, 0);
    STG(DSTA(0, 0), A0p, 0);
    STG(DSTA(0, 1), A1p, 0);
    STG(DSTB(1, 0), B0p, t1);
    STG(DSTB(1, 1), B1p, t1);
    asm volatile("s_waitcnt vmcnt(4)" ::: "memory");
    __builtin_amdgcn_s_barrier();
    __builtin_amdgcn_sched_barrier(0);
#pragma unroll
    for (int i = 0; i < 4; ++i) {
      a0[i][0] = RD(aH + i * 1024 + rb0);
      a0[i][1] = RD(aH + i * 1024 + rb1);
    }
  }

  for (int t = 0; t < NT; ++t) {
    int cur = t & 1, nxt = cur ^ 1;
    int ta = (t + 1 < NT) ? t + 1 : NT - 1;
    int tb = (t + 2 < NT) ? t + 2 : NT - 1;
    const unsigned short* aBn = aH + nxt * 32768;
    const unsigned short* bB = bH + cur * 32768;

#pragma unroll
    for (int j = 0; j < 2; ++j) {
      bS[j][0] = RD(bB + j * 1024 + rb0);
      bS[j][1] = RD(bB + j * 1024 + rb1);
    }
    STG(DSTA(nxt, 0), A0p, ta);
    PHASE_BAR();
    MQ(0, 0, a0, bS);
    PHASE_END();

#pragma unroll
    for (int j = 0; j < 2; ++j) {
      bR[j][0] = RD(bB + (2 + j) * 1024 + rb0);
      bR[j][1] = RD(bB + (2 + j) * 1024 + rb1);
    }
#pragma unroll
    for (int i = 0; i < 4; ++i) {
      a1[i][0] = RD(aH + cur * 32768 + (4 + i) * 1024 + rb0);
      a1[i][1] = RD(aH + cur * 32768 + (4 + i) * 1024 + rb1);
    }
    STG(DSTA(nxt, 1), A1p, ta);
    __builtin_amdgcn_s_barrier();
    asm volatile("s_waitcnt lgkmcnt(8)" ::: "memory");
    __builtin_amdgcn_sched_barrier(0);
    __builtin_amdgcn_s_setprio(1);
    MQ(0, 2, a0, bR);
    PHASE_END();

    STG(DSTB(cur, 0), B0p, tb);
    PHASE_BAR();
    MQ(4, 2, a1, bR);
    PHASE_END();

    STG(DSTB(cur, 1), B1p, tb);
    asm volatile("s_waitcnt vmcnt(4)" ::: "memory");
    __builtin_amdgcn_s_barrier();
#pragma unroll
    for (int i = 0; i < 4; ++i) {
      a0[i][0] = RD(aBn + i * 1024 + rb0);
      a0[i][1] = RD(aBn + i * 1024 + rb1);
    }
    __builtin_amdgcn_sched_barrier(0);
    __builtin_amdgcn_s_setprio(1);
    MQ(4, 0, a1, bS);
    PHASE_END();
  }

  // epilogue: +bias, bf16 store. C/D: col=lane&15, row=(lane>>4)*4+q
  size_t crow = m0 + (size_t)wr * 128 + hi * 4;
  size_t ccol = n0 + (size_t)wc * 64 + r15;
  unsigned short* Hp = Hout + crow * NH + ccol;
  float bv[4];
#pragma unroll
  for (int n = 0; n < 4; ++n) bv[n] = bias[ccol + n * 16];
#pragma unroll
  for (int m = 0; m < 8; ++m)
#pragma unroll
    for (int n = 0; n < 4; ++n)
#pragma unroll
      for (int q = 0; q < 4; ++q)
        Hp[(size_t)(m * 16 + q) * NH + n * 16] = f2bf(acc[m][n][q] + bv[n]);
}

// ---- layernorm + relu, wave-per-row (16 elems/lane), no LDS / no block sync
__global__ __launch_bounds__(256) void ln_relu_kernel(
    const unsigned short* __restrict__ Yb, const float* __restrict__ gamma,
    const float* __restrict__ beta, unsigned short* __restrict__ H) {
  int wid = threadIdx.x >> 6, lane = threadIdx.x & 63;
  int b = (blockIdx.x << 2) | wid;
  const unsigned short* yrow = Yb + (size_t)b * NH + lane * 16;
  bf16x8 u0 = *(const bf16x8*)&yrow[0];
  bf16x8 u1 = *(const bf16x8*)&yrow[8];
  float v[16];
#pragma unroll
  for (int i = 0; i < 8; ++i) {
    v[i] = bf2f((unsigned short)u0[i]);
    v[8 + i] = bf2f((unsigned short)u1[i]);
  }
  float s1 = 0.f, s2 = 0.f;
#pragma unroll
  for (int i = 0; i < 16; ++i) { s1 += v[i]; s2 += v[i] * v[i]; }
#pragma unroll
  for (int i = 1; i < 64; i <<= 1) {
    s1 += __shfl_xor(s1, i);
    s2 += __shfl_xor(s2, i);
  }
  float mu = s1 * (1.0f / NH);
  float var = s2 * (1.0f / NH) - mu * mu;
  float rs = rsqrtf(var + 1e-5f);
  const float4* gp = (const float4*)(gamma + lane * 16);
  const float4* bp = (const float4*)(beta + lane * 16);
  unsigned short o[16];
#pragma unroll
  for (int q = 0; q < 4; ++q) {
    float4 gg = gp[q], be = bp[q];
    o[q * 4 + 0] = f2bf(fmaxf((v[q * 4 + 0] - mu) * rs * gg.x + be.x, 0.f));
    o[q * 4 + 1] = f2bf(fmaxf((v[q * 4 + 1] - mu) * rs * gg.y + be.y, 0.f));
    o[q * 4 + 2] = f2bf(fmaxf((v[q * 4 + 2] - mu) * rs * gg.z + be.z, 0.f));
    o[q * 4 + 3] = f2bf(fmaxf((v[q * 4 + 3] - mu) * rs * gg.w + be.w, 0.f));
  }
  unsigned short* hrow = H + (size_t)b * NH + lane * 16;
  *(ulonglong2*)&hrow[0] = *(const ulonglong2*)&o[0];
  *(ulonglong2*)&hrow[8] = *(const ulonglong2*)&o[8];
}

// ---- layernorm + relu + dot(Wout) + sigmoid, wave-per-row
__global__ __launch_bounds__(256) void ln_out_kernel(
    const unsigned short* __restrict__ Yb, const float* __restrict__ gamma,
    const float* __restrict__ beta, const float* __restrict__ Wout,
    const float* __restrict__ bout, float* __restrict__ out) {
  int wid = threadIdx.x >> 6, lane = threadIdx.x & 63;
  int b = (blockIdx.x << 2) | wid;
  const unsigned short* yrow = Yb + (size_t)b * NH + lane * 16;
  bf16x8 u0 = *(const bf16x8*)&yrow[0];
  bf16x8 u1 = *(const bf16x8*)&yrow[8];
  float v[16];
#pragma unroll
  for (int i = 0; i < 8; ++i) {
    v[i] = bf2f((unsigned short)u0[i]);
    v[8 + i] = bf2f((unsigned short)u1[i]);
  }
  float s1 = 0.f, s2 = 0.f;
#pragma unroll
  for (int i = 0; i < 16; ++i) { s1 += v[i]; s2 += v[i] * v[i]; }
#pragma unroll
  for (int i = 1; i < 64; i <<= 1) {
    s1 += __shfl_xor(s1, i);
    s2 += __shfl_xor(s2, i);
  }
  float mu = s1 * (1.0f / NH);
  float var = s2 * (1.0f / NH) - mu * mu;
  float rs = rsqrtf(var + 1e-5f);
  const float4* gp = (const float4*)(gamma + lane * 16);
  const float4* bp = (const float4*)(beta + lane * 16);
  const float4* wp = (const float4*)(Wout + lane * 16);
  float s = 0.f;
#pragma unroll
  for (int q = 0; q < 4; ++q) {
    float4 gg = gp[q], be = bp[q], wo = wp[q];
    s += fmaxf((v[q * 4 + 0] - mu) * rs * gg.x + be.x, 0.f) * wo.x;
    s += fmaxf((v[q * 4 + 1] - mu) * rs * gg.y + be.y, 0.f) * wo.y;
    s += fmaxf((v[q * 4 + 2] - mu) * rs * gg.z + be.z, 0.f) * wo.z;
    s += fmaxf((v[q * 4 + 3] - mu) * rs * gg.w + be.w, 0.f) * wo.w;
  }
#pragma unroll
  for (int i = 1; i < 64; i <<= 1) s += __shfl_xor(s, i);
  if (lane == 0) out[b] = 1.f / (1.f + expf(-(s + bout[0])));
}

extern "C" void kernel_launch(void* const* d_in, const int* in_sizes, int n_in,
                              void* d_out, int out_size, void* d_ws, size_t ws_size,
                              hipStream_t stream) {
  const float* conts = (const float*)d_in[0];
  const int* cates = (const int*)d_in[1];
  const float* emb  = (const float*)d_in[3];
  const float* W1   = (const float*)d_in[4];
  const float* b1   = (const float*)d_in[5];
  const float* ln1g = (const float*)d_in[6];
  const float* ln1b = (const float*)d_in[7];
  const float* W2   = (const float*)d_in[8];
  const float* b2   = (const float*)d_in[9];
  const float* ln2g = (const float*)d_in[10];
  const float* ln2b = (const float*)d_in[11];
  const float* Wout = (const float*)d_in[12];
  const float* bout = (const float*)d_in[13];
  float* out = (float*)d_out;

  unsigned short* X   = (unsigned short*)d_ws;            // BATCH * KX
  unsigned short* W1t = X + (size_t)BATCH * KX;           // NH * KX
  unsigned short* W2t = W1t + (size_t)NH * KX;            // NH * NH
  unsigned short* H1  = W2t + (size_t)NH * NH;            // BATCH * NH
  unsigned short* Yb1 = H1 + (size_t)BATCH * NH;          // BATCH * NH
  unsigned short* Yb2 = Yb1 + (size_t)BATCH * NH;         // BATCH * NH

  hipLaunchKernelGGL(prep_kernel, dim3(FEAT_BLOCKS + WPREP_BLOCKS), dim3(256), 0, stream,
                     conts, cates, emb, X, W1, W2, W1t, W2t);
  hipLaunchKernelGGL(gemm_8ph, dim3(256), dim3(512), 0, stream,
                     X, W1t, b1, Yb1, KX, KX / 64);
  hipLaunchKernelGGL(ln_relu_kernel, dim3(BATCH / 4), dim3(256), 0, stream,
                     Yb1, ln1g, ln1b, H1);
  hipLaunchKernelGGL(gemm_8ph, dim3(256), dim3(512), 0, stream,
                     H1, W2t, b2, Yb2, NH, NH / 64);
  hipLaunchKernelGGL(ln_out_kernel, dim3(BATCH / 4), dim3(256), 0, stream,
                     Yb2, ln2g, ln2b, Wout, bout, out);
}

// Round 11
// 168.614 us; speedup vs baseline: 1.3510x; 1.0145x over previous
//
#include <hip/hip_runtime.h>
#include <hip/hip_bf16.h>

#define BATCH 16384
#define NH 1024
#define NF 39
#define CCLD 72
#define KX 2432      // GEMM1 K: [0:13 conts][13:16 pad0][16:1680 cate flat][1680:2421 pairs][2421:2432 pad0]
#define NPAIR 741
#define FEAT_BLOCKS (BATCH / 4)           // 4096
#define WPREP_BX (KX / 32 + NH / 32)      // 108
#define WPREP_BLOCKS (WPREP_BX * (NH / 32))  // 3456

typedef __attribute__((ext_vector_type(8))) short bf16x8;
typedef __attribute__((ext_vector_type(4))) float f32x4;

typedef const __attribute__((address_space(1))) unsigned int* gptr_t;
typedef __attribute__((address_space(3))) unsigned int* lptr_t;

__device__ __forceinline__ float bf2f(unsigned short u) {
  union { unsigned int i; float f; } c; c.i = ((unsigned int)u) << 16; return c.f;
}
__device__ __forceinline__ unsigned short f2bf(float f) {
  union { float f; unsigned int i; } c; c.f = f;
  unsigned int r = c.i + 0x7FFFu + ((c.i >> 16) & 1u);
  return (unsigned short)(r >> 16);
}

// ===== merged prep: blocks [0,4096) = features; [4096, 7552) = W1t/W2t build =====
__global__ __launch_bounds__(256) void prep_kernel(
    const float* __restrict__ conts, const int* __restrict__ cates,
    const float* __restrict__ emb, unsigned short* __restrict__ X,
    const float* __restrict__ W1, const float* __restrict__ W2,
    unsigned short* __restrict__ W1t, unsigned short* __restrict__ W2t) {
  __shared__ __align__(16) unsigned char smem[33664];

  if (blockIdx.x >= FEAT_BLOCKS) {
    int wq = blockIdx.x - FEAT_BLOCKS;
    int bx = wq % WPREP_BX;
    int nb = (wq / WPREP_BX) * 32;
    float (*tile)[33] = (float(*)[33])smem;
    int tx = threadIdx.x & 31, ty = threadIdx.x >> 5;
    if (bx < KX / 32) {
      int kb = bx * 32;
#pragma unroll
      for (int i = 0; i < 32; i += 8) {
        int k = kb + ty + i;
        float v = 0.f;
        if (k < 13) {
          float s = 0.f;
#pragma unroll 8
          for (int d = 0; d < 64; ++d)
            s += emb[k * 64 + d] * W1[(size_t)(k * 64 + d) * NH + nb + tx];
          v = s;
        } else if (k >= 16 && k < 1680) {
          v = W1[(size_t)(832 + k - 16) * NH + nb + tx];
        } else if (k >= 1680 && k < 1680 + NPAIR) {
          v = W1[(size_t)(2496 + k - 1680) * NH + nb + tx];
        }
        tile[ty + i][tx] = v;
      }
      __syncthreads();
#pragma unroll
      for (int i = 0; i < 32; i += 8)
        W1t[(size_t)(nb + ty + i) * KX + kb + tx] = f2bf(tile[tx][ty + i]);
    } else {
      int kb = (bx - KX / 32) * 32;
#pragma unroll
      for (int i = 0; i < 32; i += 8)
        tile[ty + i][tx] = W2[(size_t)(kb + ty + i) * NH + nb + tx];
      __syncthreads();
#pragma unroll
      for (int i = 0; i < 32; i += 8)
        W2t[(size_t)(nb + ty + i) * NH + kb + tx] = f2bf(tile[tx][ty + i]);
    }
    return;
  }

  int wid = threadIdx.x >> 6, lane = threadIdx.x & 63;
  int b = (blockIdx.x << 2) | wid;
  unsigned short* my = (unsigned short*)smem + wid * (48 * CCLD);
  unsigned short* pw = (unsigned short*)(smem + 27648) + wid * 752;
  unsigned short* Xrow = X + (size_t)b * KX;

  int2 c2[13];
#pragma unroll
  for (int i = 0; i < 13; ++i)
    c2[i] = ((const int2*)(cates + b * 26))[i];
  float cf[13];
#pragma unroll
  for (int f = 0; f < 13; ++f) cf[f] = conts[b * 13 + f];
  float cemb[13];
#pragma unroll
  for (int f = 0; f < 13; ++f) cemb[f] = emb[f * 64 + lane];
  float g[26];
#pragma unroll
  for (int j = 0; j < 26; ++j) {
    int idx = (j & 1) ? c2[j >> 1].y : c2[j >> 1].x;
    g[j] = emb[(size_t)idx * 64 + lane];
  }
#pragma unroll
  for (int f = 0; f < 13; ++f)
    my[f * CCLD + lane] = f2bf(cemb[f] * cf[f]);
#pragma unroll
  for (int j = 0; j < 26; ++j)
    my[(13 + j) * CCLD + lane] = f2bf(g[j]);
#pragma unroll
  for (int f = NF; f < 48; ++f) my[f * CCLD + lane] = 0;
  if (lane < 16) Xrow[lane] = (lane < 13) ? f2bf(cf[lane]) : 0;
  if (lane < 752 - NPAIR) pw[NPAIR + lane] = 0;
  __syncthreads();

#pragma unroll
  for (int i = 0; i < 4; ++i) {
    int q = i * 64 + lane;
    if (q < 208)
      *(bf16x8*)&Xrow[16 + q * 8] =
          *(const bf16x8*)&my[(13 + (q >> 3)) * CCLD + (q & 7) * 8];
  }

  int r15 = lane & 15, hi = lane >> 4;
  bf16x8 fr[2][3];
#pragma unroll
  for (int t = 0; t < 3; ++t)
#pragma unroll
    for (int h = 0; h < 2; ++h)
      fr[h][t] = *(const bf16x8*)&my[(t * 16 + r15) * CCLD + h * 32 + hi * 8];

  f32x4 acc[3][3];
#pragma unroll
  for (int it = 0; it < 3; ++it)
#pragma unroll
    for (int jt = 0; jt < 3; ++jt)
      acc[it][jt] = (f32x4){0.f, 0.f, 0.f, 0.f};
#pragma unroll
  for (int h = 0; h < 2; ++h)
#pragma unroll
    for (int it = 0; it < 3; ++it)
#pragma unroll
      for (int jt = 0; jt < 3; ++jt)
        acc[it][jt] = __builtin_amdgcn_mfma_f32_16x16x32_bf16(
            fr[h][it], fr[h][jt], acc[it][jt], 0, 0, 0);

#pragma unroll
  for (int it = 0; it < 3; ++it)
#pragma unroll
    for (int jt = 0; jt < 3; ++jt) {
      int g_ = jt * 16 + r15;
#pragma unroll
      for (int r = 0; r < 4; ++r) {
        int f = it * 16 + hi * 4 + r;
        if (f < g_ && g_ < NF) {
          int p = f * 38 - ((f * (f - 1)) >> 1) + g_ - f - 1;
          pw[p] = f2bf(acc[it][jt][r]);
        }
      }
    }
  __syncthreads();

#pragma unroll
  for (int i = 0; i < 2; ++i) {
    int q = i * 64 + lane;
    if (q < 94)
      *(bf16x8*)&Xrow[1680 + q * 8] = *(const bf16x8*)&pw[q * 8];
  }
}

// ====== 256x256 GEMM: minimal-barrier deep-prefetch (2 barriers/tile, stage t+2) ======
// R0: rd bS(B01,t); lgkm0; MQ(0,0)                                [no barrier]
// R1: rd bR,a1; lgkm(8); MQ(0,2); lgkm(0); BARRIER-1              [all t-reads done]
// R2: STG B0,A0,A1 (t+2)  [regions' t-readers drained]; MQ(4,2)
// R3: STG B1(t+2); vmcnt(8) [drains t+1 batch, issued 1 tile ago]; BARRIER-2;
//     rd a0(t+1); MQ(4,0)
// In-flight <= 16 GLL/wave. MFMA order identical to r6 => bit-identical results.
#define GLL(s_, d_) __builtin_amdgcn_global_load_lds((gptr_t)(s_), (lptr_t)(d_), 16, 0, 0)
#define RD(p_) (*(const bf16x8*)(p_))
#define DSTA(buf, h) (lds + (buf) * 32768 + (h) * 8192 + sd)
#define DSTB(buf, h) (lds + (buf) * 32768 + 16384 + (h) * 8192 + sd)
#define STG(dst, srcb, tau) do { \
    const unsigned short* _s = (srcb) + (size_t)(tau) * 64; \
    GLL(_s, dst); GLL(_s + (size_t)64 * K, (dst) + 4096); } while (0)
#define FENCE() __builtin_amdgcn_sched_barrier(0)
#define MQ(I0, J0, AB, BB) do { \
    _Pragma("unroll") \
    for (int i_ = 0; i_ < 4; ++i_) \
      _Pragma("unroll") \
      for (int j_ = 0; j_ < 2; ++j_) { \
        acc[(I0) + i_][(J0) + j_] = __builtin_amdgcn_mfma_f32_16x16x32_bf16( \
            AB[i_][0], BB[j_][0], acc[(I0) + i_][(J0) + j_], 0, 0, 0); \
        acc[(I0) + i_][(J0) + j_] = __builtin_amdgcn_mfma_f32_16x16x32_bf16( \
            AB[i_][1], BB[j_][1], acc[(I0) + i_][(J0) + j_], 0, 0, 0); \
      } } while (0)

__global__ __launch_bounds__(512, 2) void gemm_8ph(
    const unsigned short* __restrict__ A, const unsigned short* __restrict__ Bt,
    const float* __restrict__ bias, unsigned short* __restrict__ Hout,
    int K, int NT) {
  __shared__ unsigned short lds[65536];

  int bid = blockIdx.x;
  int swz = (bid & 7) * 32 + (bid >> 3);
  int mb = swz >> 2, nb = swz & 3;
  size_t m0 = (size_t)mb * 256, n0 = (size_t)nb * 256;

  int tid = threadIdx.x, lane = tid & 63, w = tid >> 6;
  int wr = w >> 2, wc = w & 3;
  int r15 = lane & 15, hi = lane >> 4;

  int sr = tid >> 3;
  int ce = ((tid & 7) ^ (sr & 7)) << 3;
  int sd = tid * 8;
  const unsigned short* A0p = A + (m0 + sr) * (size_t)K + ce;
  const unsigned short* A1p = A0p + (size_t)128 * K;
  const unsigned short* B0p = Bt + (n0 + sr) * (size_t)K + ce;
  const unsigned short* B1p = B0p + (size_t)128 * K;

  int cbs = (((hi << 4) ^ ((r15 & 7) << 4)) >> 1);
  int rb0 = r15 * 64 + cbs;
  int rb1 = rb0 ^ 32;
  const unsigned short* aH = lds + wr * 8192;
  const unsigned short* bH = lds + 16384 + (wc >> 1) * 8192 + (wc & 1) * 4096;

  f32x4 acc[8][4];
#pragma unroll
  for (int m = 0; m < 8; ++m)
#pragma unroll
    for (int n = 0; n < 4; ++n) acc[m][n] = (f32x4){0.f, 0.f, 0.f, 0.f};

  bf16x8 a0[4][2], a1[4][2], bS[2][2], bR[2][2];

  // ---- prologue: stage batch0 {A(0),B(0)}, batch1 {A(1),B(1)}; vmcnt(8) -> batch0
  // landed; barrier; pre-read a0(0).
  {
    int t1 = (NT > 1) ? 1 : 0;
    STG(DSTA(0, 0), A0p, 0);
    STG(DSTA(0, 1), A1p, 0);
    STG(DSTB(0, 0), B0p, 0);
    STG(DSTB(0, 1), B1p, 0);
    STG(DSTA(1, 0), A0p, t1);
    STG(DSTA(1, 1), A1p, t1);
    STG(DSTB(1, 0), B0p, t1);
    STG(DSTB(1, 1), B1p, t1);
    asm volatile("s_waitcnt vmcnt(8)" ::: "memory");
    asm volatile("s_barrier" ::: "memory");
    FENCE();
#pragma unroll
    for (int i = 0; i < 4; ++i) {
      a0[i][0] = RD(aH + i * 1024 + rb0);
      a0[i][1] = RD(aH + i * 1024 + rb1);
    }
  }

  for (int t = 0; t < NT; ++t) {
    int cur = t & 1, nxt = cur ^ 1;
    int tc = (t + 2 < NT) ? t + 2 : NT - 1;   // clamped dummy stays in-bounds
    const unsigned short* aBc = aH + cur * 32768;
    const unsigned short* aBn = aH + nxt * 32768;
    const unsigned short* bB = bH + cur * 32768;

    // ---- R0: rd bS = B01(t); MQ(0,0)
#pragma unroll
    for (int j = 0; j < 2; ++j) {
      bS[j][0] = RD(bB + j * 1024 + rb0);
      bS[j][1] = RD(bB + j * 1024 + rb1);
    }
    asm volatile("s_waitcnt lgkmcnt(0)" ::: "memory");
    FENCE();
    __builtin_amdgcn_s_setprio(1);
    MQ(0, 0, a0, bS);
    __builtin_amdgcn_s_setprio(0);
    FENCE();

    // ---- R1: rd bR + a1; lgkm(8) [bR done]; MQ(0,2); lgkm(0) [a1 done]; BARRIER-1
#pragma unroll
    for (int j = 0; j < 2; ++j) {
      bR[j][0] = RD(bB + (2 + j) * 1024 + rb0);
      bR[j][1] = RD(bB + (2 + j) * 1024 + rb1);
    }
#pragma unroll
    for (int i = 0; i < 4; ++i) {
      a1[i][0] = RD(aBc + (4 + i) * 1024 + rb0);
      a1[i][1] = RD(aBc + (4 + i) * 1024 + rb1);
    }
    asm volatile("s_waitcnt lgkmcnt(8)" ::: "memory");
    FENCE();
    __builtin_amdgcn_s_setprio(1);
    MQ(0, 2, a0, bR);
    __builtin_amdgcn_s_setprio(0);
    asm volatile("s_waitcnt lgkmcnt(0)" ::: "memory");
    asm volatile("s_barrier" ::: "memory");   // BARRIER-1: all tile-t LDS reads done
    FENCE();

    // ---- R2: STG B0,A0,A1 (t+2) into just-freed regions; MQ(4,2)
    STG(DSTB(cur, 0), B0p, tc);
    STG(DSTA(cur, 0), A0p, tc);
    STG(DSTA(cur, 1), A1p, tc);
    __builtin_amdgcn_s_setprio(1);
    MQ(4, 2, a1, bR);
    __builtin_amdgcn_s_setprio(0);
    FENCE();

    // ---- R3: STG B1(t+2); vmcnt(8) drains t+1 batch; BARRIER-2; rd a0(t+1); MQ(4,0)
    STG(DSTB(cur, 1), B1p, tc);
    asm volatile("s_waitcnt vmcnt(8)" ::: "memory");
    asm volatile("s_barrier" ::: "memory");   // BARRIER-2: A(t+1)/B(t+1) visible to all
    FENCE();
#pragma unroll
    for (int i = 0; i < 4; ++i) {
      a0[i][0] = RD(aBn + i * 1024 + rb0);
      a0[i][1] = RD(aBn + i * 1024 + rb1);
    }
    FENCE();
    __builtin_amdgcn_s_setprio(1);
    MQ(4, 0, a1, bS);
    __builtin_amdgcn_s_setprio(0);
    FENCE();
  }

  // epilogue: +bias, bf16 store. C/D: col=lane&15, row=(lane>>4)*4+q
  size_t crow = m0 + (size_t)wr * 128 + hi * 4;
  size_t ccol = n0 + (size_t)wc * 64 + r15;
  unsigned short* Hp = Hout + crow * NH + ccol;
  float bv[4];
#pragma unroll
  for (int n = 0; n < 4; ++n) bv[n] = bias[ccol + n * 16];
#pragma unroll
  for (int m = 0; m < 8; ++m)
#pragma unroll
    for (int n = 0; n < 4; ++n)
#pragma unroll
      for (int q = 0; q < 4; ++q)
        Hp[(size_t)(m * 16 + q) * NH + n * 16] = f2bf(acc[m][n][q] + bv[n]);
}

// ---- layernorm + relu, wave-per-row
__global__ __launch_bounds__(256) void ln_relu_kernel(
    const unsigned short* __restrict__ Yb, const float* __restrict__ gamma,
    const float* __restrict__ beta, unsigned short* __restrict__ H) {
  int wid = threadIdx.x >> 6, lane = threadIdx.x & 63;
  int b = (blockIdx.x << 2) | wid;
  const unsigned short* yrow = Yb + (size_t)b * NH + lane * 16;
  bf16x8 u0 = *(const bf16x8*)&yrow[0];
  bf16x8 u1 = *(const bf16x8*)&yrow[8];
  float v[16];
#pragma unroll
  for (int i = 0; i < 8; ++i) {
    v[i] = bf2f((unsigned short)u0[i]);
    v[8 + i] = bf2f((unsigned short)u1[i]);
  }
  float s1 = 0.f, s2 = 0.f;
#pragma unroll
  for (int i = 0; i < 16; ++i) { s1 += v[i]; s2 += v[i] * v[i]; }
#pragma unroll
  for (int i = 1; i < 64; i <<= 1) {
    s1 += __shfl_xor(s1, i);
    s2 += __shfl_xor(s2, i);
  }
  float mu = s1 * (1.0f / NH);
  float var = s2 * (1.0f / NH) - mu * mu;
  float rs = rsqrtf(var + 1e-5f);
  const float4* gp = (const float4*)(gamma + lane * 16);
  const float4* bp = (const float4*)(beta + lane * 16);
  unsigned short o[16];
#pragma unroll
  for (int q = 0; q < 4; ++q) {
    float4 gg = gp[q], be = bp[q];
    o[q * 4 + 0] = f2bf(fmaxf((v[q * 4 + 0] - mu) * rs * gg.x + be.x, 0.f));
    o[q * 4 + 1] = f2bf(fmaxf((v[q * 4 + 1] - mu) * rs * gg.y + be.y, 0.f));
    o[q * 4 + 2] = f2bf(fmaxf((v[q * 4 + 2] - mu) * rs * gg.z + be.z, 0.f));
    o[q * 4 + 3] = f2bf(fmaxf((v[q * 4 + 3] - mu) * rs * gg.w + be.w, 0.f));
  }
  unsigned short* hrow = H + (size_t)b * NH + lane * 16;
  *(ulonglong2*)&hrow[0] = *(const ulonglong2*)&o[0];
  *(ulonglong2*)&hrow[8] = *(const ulonglong2*)&o[8];
}

// ---- layernorm + relu + dot(Wout) + sigmoid, wave-per-row
__global__ __launch_bounds__(256) void ln_out_kernel(
    const unsigned short* __restrict__ Yb, const float* __restrict__ gamma,
    const float* __restrict__ beta, const float* __restrict__ Wout,
    const float* __restrict__ bout, float* __restrict__ out) {
  int wid = threadIdx.x >> 6, lane = threadIdx.x & 63;
  int b = (blockIdx.x << 2) | wid;
  const unsigned short* yrow = Yb + (size_t)b * NH + lane * 16;
  bf16x8 u0 = *(const bf16x8*)&yrow[0];
  bf16x8 u1 = *(const bf16x8*)&yrow[8];
  float v[16];
#pragma unroll
  for (int i = 0; i < 8; ++i) {
    v[i] = bf2f((unsigned short)u0[i]);
    v[8 + i] = bf2f((unsigned short)u1[i]);
  }
  float s1 = 0.f, s2 = 0.f;
#pragma unroll
  for (int i = 0; i < 16; ++i) { s1 += v[i]; s2 += v[i] * v[i]; }
#pragma unroll
  for (int i = 1; i < 64; i <<= 1) {
    s1 += __shfl_xor(s1, i);
    s2 += __shfl_xor(s2, i);
  }
  float mu = s1 * (1.0f / NH);
  float var = s2 * (1.0f / NH) - mu * mu;
  float rs = rsqrtf(var + 1e-5f);
  const float4* gp = (const float4*)(gamma + lane * 16);
  const float4* bp = (const float4*)(beta + lane * 16);
  const float4* wp = (const float4*)(Wout + lane * 16);
  float s = 0.f;
#pragma unroll
  for (int q = 0; q < 4; ++q) {
    float4 gg = gp[q], be = bp[q], wo = wp[q];
    s += fmaxf((v[q * 4 + 0] - mu) * rs * gg.x + be.x, 0.f) * wo.x;
    s += fmaxf((v[q * 4 + 1] - mu) * rs * gg.y + be.y, 0.f) * wo.y;
    s += fmaxf((v[q * 4 + 2] - mu) * rs * gg.z + be.z, 0.f) * wo.z;
    s += fmaxf((v[q * 4 + 3] - mu) * rs * gg.w + be.w, 0.f) * wo.w;
  }
#pragma unroll
  for (int i = 1; i < 64; i <<= 1) s += __shfl_xor(s, i);
  if (lane == 0) out[b] = 1.f / (1.f + expf(-(s + bout[0])));
}

extern "C" void kernel_launch(void* const* d_in, const int* in_sizes, int n_in,
                              void* d_out, int out_size, void* d_ws, size_t ws_size,
                              hipStream_t stream) {
  const float* conts = (const float*)d_in[0];
  const int* cates = (const int*)d_in[1];
  const float* emb  = (const float*)d_in[3];
  const float* W1   = (const float*)d_in[4];
  const float* b1   = (const float*)d_in[5];
  const float* ln1g = (const float*)d_in[6];
  const float* ln1b = (const float*)d_in[7];
  const float* W2   = (const float*)d_in[8];
  const float* b2   = (const float*)d_in[9];
  const float* ln2g = (const float*)d_in[10];
  const float* ln2b = (const float*)d_in[11];
  const float* Wout = (const float*)d_in[12];
  const float* bout = (const float*)d_in[13];
  float* out = (float*)d_out;

  unsigned short* X   = (unsigned short*)d_ws;            // BATCH * KX
  unsigned short* W1t = X + (size_t)BATCH * KX;           // NH * KX
  unsigned short* W2t = W1t + (size_t)NH * KX;            // NH * NH
  unsigned short* H1  = W2t + (size_t)NH * NH;            // BATCH * NH
  unsigned short* Yb1 = H1 + (size_t)BATCH * NH;          // BATCH * NH
  unsigned short* Yb2 = Yb1 + (size_t)BATCH * NH;         // BATCH * NH

  hipLaunchKernelGGL(prep_kernel, dim3(FEAT_BLOCKS + WPREP_BLOCKS), dim3(256), 0, stream,
                     conts, cates, emb, X, W1, W2, W1t, W2t);
  hipLaunchKernelGGL(gemm_8ph, dim3(256), dim3(512), 0, stream,
                     X, W1t, b1, Yb1, KX, KX / 64);
  hipLaunchKernelGGL(ln_relu_kernel, dim3(BATCH / 4), dim3(256), 0, stream,
                     Yb1, ln1g, ln1b, H1);
  hipLaunchKernelGGL(gemm_8ph, dim3(256), dim3(512), 0, stream,
                     H1, W2t, b2, Yb2, NH, NH / 64);
  hipLaunchKernelGGL(ln_out_kernel, dim3(BATCH / 4), dim3(256), 0, stream,
                     Yb2, ln2g, ln2b, Wout, bout, out);
}